// Round 18
// baseline (3149.832 us; speedup 1.0000x reference)
//
#include <hip/hip_runtime.h>
#include <hip/hip_bf16.h>
#include <cstddef>
#include <cstdint>

typedef __attribute__((ext_vector_type(8))) short short8;
typedef __attribute__((ext_vector_type(4))) float f32x4;
typedef unsigned short u16;
typedef unsigned int u32;

#define B_ 512
#define T_ 48
#define F_ 2048
#define U_ 2048
#define G4 8192
#define OT 24

__device__ __forceinline__ u16 f2bf(float f) {
    __hip_bfloat16 b = __float2bfloat16(f);
    return *reinterpret_cast<u16*>(&b);
}
__device__ __forceinline__ float bf2f(u16 v) {
    union { u32 u; float f; } c;
    c.u = ((u32)v) << 16;
    return c.f;
}

__device__ __forceinline__ void gl_lds16(const void* g, void* l) {
    __builtin_amdgcn_global_load_lds(
        (const __attribute__((address_space(1))) void*)g,
        (__attribute__((address_space(3))) void*)l, 16, 0, 0);
}

// ---------------------------------------------------------------------------
// XCD/L2-aware tile mapping (proven r6/r7).
// ---------------------------------------------------------------------------
__device__ __forceinline__ void map_tile(int BM, int BN, int& m0, int& n0) {
    const int gx = gridDim.x, gy = gridDim.y;
    int lin = blockIdx.y * gx + blockIdx.x;
    const int nwg = gx * gy;
    const int sn = gx >> 3;
    const int EN = (sn >= 4) ? 4 : sn;
    const int EM = 4;
    bool ok = ((gx & 7) == 0) && ((gy & 3) == 0) && (sn < 4 || (sn & 3) == 0);
    if (ok) {
        int xcd = lin & 7, idx = lin >> 3;
        int epw = EM * EN;
        int e = idx / epw, r = idx % epw;
        int meb = gy / EM;
        int ne = e / meb, me = e % meb;
        int mi = r % EM, nli = r / EM;
        m0 = (me * EM + mi) * BM;
        n0 = (xcd * sn + ne * EN + nli) * BN;
    } else {
        if ((nwg & 7) == 0) {
            int q = nwg >> 3;
            lin = (lin & 7) * q + (lin >> 3);
        }
        m0 = (lin / gx) * BM;
        n0 = (lin % gx) * BN;
    }
}

// ---------------------------------------------------------------------------
// fp32 [R][C] -> bf16 [C][R]; ILV=1 -> gate-interleaved rows n'=(u<<2)|g.
// ---------------------------------------------------------------------------
template <int ILV>
__global__ void transpose_f32_bf16(const float* __restrict__ in,
                                   u16* __restrict__ out, int R, int C) {
    __shared__ float tile[32][33];
    int bx = blockIdx.x * 32;
    int by = blockIdx.y * 32;
    int tx = threadIdx.x, ty = threadIdx.y;
#pragma unroll
    for (int j = 0; j < 32; j += 8)
        tile[ty + j][tx] = in[(size_t)(by + ty + j) * C + bx + tx];
    __syncthreads();
#pragma unroll
    for (int j = 0; j < 32; j += 8) {
        int cidx = bx + ty + j;
        int orow = ILV ? (((cidx & 2047) << 2) | (cidx >> 11)) : cidx;
        out[(size_t)orow * R + by + tx] = f2bf(tile[tx][ty + j]);
    }
}

__global__ void cvt_bf16(const float* __restrict__ in, u16* __restrict__ out, long n) {
    long i = ((long)blockIdx.x * blockDim.x + threadIdx.x) * 4;
    if (i >= n) return;
    f32x4 v = *(const f32x4*)(in + i);
    ushort4 o;
    o.x = f2bf(v[0]); o.y = f2bf(v[1]); o.z = f2bf(v[2]); o.w = f2bf(v[3]);
    *(ushort4*)(out + i) = o;
}

// x [b][t][f] fp32 -> xbf [t][b][f] bf16
__global__ void cvt_x_tmajor(const float* __restrict__ x, u16* __restrict__ xbf) {
    long i = ((long)blockIdx.x * blockDim.x + threadIdx.x) * 4;
    int f = (int)(i & (F_ - 1));
    long bt = i >> 11;
    int t = (int)(bt % T_);
    int b = (int)(bt / T_);
    f32x4 v = *(const f32x4*)(x + i);
    ushort4 o;
    o.x = f2bf(v[0]); o.y = f2bf(v[1]); o.z = f2bf(v[2]); o.w = f2bf(v[3]);
    *(ushort4*)(xbf + ((size_t)t * B_ + b) * F_ + f) = o;
}

__global__ void make_bias4(const float* __restrict__ bias, float* __restrict__ b4) {
    int n = blockIdx.x * 256 + threadIdx.x;
    int g = n & 3, u = n >> 2;
    b4[n] = bias[g * 2048 + u];
}

__global__ void bcomb_k(const u16* __restrict__ W4kT, const float* __restrict__ bd,
                        const float* __restrict__ bias4, float* __restrict__ bc) {
    int lane = threadIdx.x & 63, wid = threadIdx.x >> 6;
    int n = blockIdx.x * 4 + wid;
    const u16* row = W4kT + (size_t)n * U_;
    float s = 0.f;
    for (int j0 = lane * 8; j0 < U_; j0 += 512) {
        short8 v = *(const short8*)&row[j0];
#pragma unroll
        for (int e = 0; e < 8; ++e) s += bd[j0 + e] * bf2f((u16)v[e]);
    }
#pragma unroll
    for (int o = 32; o; o >>= 1) s += __shfl_down(s, o);
    if (lane == 0) bc[n] = bias4[n] + s;
}

// ---------------------------------------------------------------------------
// Counted-vmcnt GEMM pipeline (coarse, proven r7/r15).
// ---------------------------------------------------------------------------
template <int BM, int BN, int WR, int WC, int TPB, int NBUF>
__device__ __forceinline__ void gpipe(const u16* __restrict__ A, long lda,
                                      const u16* __restrict__ B, int K,
                                      int m0, int n0, int tid, u16* lds,
                                      f32x4 (&acc)[BM / WR / 16][BN / WC / 16]) {
    constexpr int BK = 64;
    constexpr int MF = BM / WR / 16, NF = BN / WC / 16;
    constexpr int TILE = (BM + BN) * BK;
    constexpr int LA = BM * BK / (TPB * 8);
    constexpr int LB = BN * BK / (TPB * 8);
    constexpr int LPS = LA + LB;
    static_assert((NBUF == 3 && (LPS == 4 || LPS == 6)) ||
                  (NBUF == 2 && (LPS == 6 || LPS == 8)), "vmcnt table");
    const int lane = tid & 63, wid = tid >> 6;
    const int wr = wid / WC, wc = wid % WC;
    const int r16 = lane & 15, kg = lane >> 4;
    const int kpar = wid & 1;
    const int NT = K / BK;

    auto stage = [&](int t) {
        if (t >= NT) return;
        const u16* Abase = A + (size_t)m0 * lda + (size_t)t * BK;
        const u16* Bbase = B + (size_t)n0 * (size_t)K + (size_t)t * BK;
        u16* dst = lds + (t % NBUF) * TILE;
#pragma unroll
        for (int i = 0; i < LA; ++i) {
            int idx = i * TPB + tid;
            int r = idx >> 3, sl = idx & 7;
            gl_lds16(Abase + (size_t)r * lda + ((sl ^ (r & 7)) * 8), dst + idx * 8);
        }
        u16* dstB = dst + BM * BK;
#pragma unroll
        for (int i = 0; i < LB; ++i) {
            int idx = i * TPB + tid;
            int r = idx >> 3, sl = idx & 7;
            gl_lds16(Bbase + (size_t)r * (size_t)K + ((sl ^ (r & 7)) * 8), dstB + idx * 8);
        }
    };
    auto compute = [&](int t) {
        const u16* Ab = lds + (t % NBUF) * TILE;
        const u16* Bb = Ab + BM * BK;
        __builtin_amdgcn_s_setprio(1);
#pragma unroll
        for (int ks2 = 0; ks2 < 2; ++ks2) {
            const int ks = ks2 ^ kpar;
            short8 af[MF], bf[NF];
#pragma unroll
            for (int mi = 0; mi < MF; ++mi) {
                int row = wr * (BM / WR) + mi * 16 + r16;
                int s = (ks * 4 + kg) ^ (row & 7);
                af[mi] = *(const short8*)&Ab[row * BK + s * 8];
            }
#pragma unroll
            for (int ni = 0; ni < NF; ++ni) {
                int row = wc * (BN / WC) + ni * 16 + r16;
                int s = (ks * 4 + kg) ^ (row & 7);
                bf[ni] = *(const short8*)&Bb[row * BK + s * 8];
            }
#pragma unroll
            for (int mi = 0; mi < MF; ++mi)
#pragma unroll
                for (int ni = 0; ni < NF; ++ni)
                    acc[mi][ni] = __builtin_amdgcn_mfma_f32_16x16x32_bf16(
                        af[mi], bf[ni], acc[mi][ni], 0, 0, 0);
        }
        __builtin_amdgcn_s_setprio(0);
    };

    if constexpr (NBUF == 3) {
        stage(0);
        stage(1);
        for (int t = 0; t < NT; ++t) {
            stage(t + 2);
            if (t + 2 < NT) {
                if constexpr (LPS == 6)
                    asm volatile("s_waitcnt vmcnt(12)\ns_barrier" ::: "memory");
                else
                    asm volatile("s_waitcnt vmcnt(8)\ns_barrier" ::: "memory");
            } else if (t + 1 < NT) {
                if constexpr (LPS == 6)
                    asm volatile("s_waitcnt vmcnt(6)\ns_barrier" ::: "memory");
                else
                    asm volatile("s_waitcnt vmcnt(4)\ns_barrier" ::: "memory");
            } else {
                asm volatile("s_waitcnt vmcnt(0)\ns_barrier" ::: "memory");
            }
            compute(t);
            asm volatile("s_barrier" ::: "memory");
        }
    } else {
        stage(0);
        for (int t = 0; t < NT; ++t) {
            stage(t + 1);
            if (t + 1 < NT) {
                if constexpr (LPS == 8)
                    asm volatile("s_waitcnt vmcnt(8)\ns_barrier" ::: "memory");
                else
                    asm volatile("s_waitcnt vmcnt(6)\ns_barrier" ::: "memory");
            } else {
                asm volatile("s_waitcnt vmcnt(0)\ns_barrier" ::: "memory");
            }
            compute(t);
            asm volatile("s_barrier" ::: "memory");
        }
    }
}

// CM: 0 none, 2 bf16 Cinit. OUTM: 0 fp32, 1 bf16, 2 fp32 (t,b)-remap,
// 3 fp32 (ldc) + bf16 secondary (ldc2).
template <int BM, int BN, int WR, int WC, int TPB, int NBUF, int CM, int BIAS, int OUTM>
__global__ __launch_bounds__(TPB) void gemm3(
    const u16* __restrict__ A1, long lda1, const u16* __restrict__ B1, int K1,
    const void* __restrict__ Ci, long ldci, const float* __restrict__ bias,
    void* __restrict__ Co, long ldc, void* __restrict__ Co2, long ldc2) {
    __shared__ __align__(16) u16 lds[NBUF * (BM + BN) * 64];
    int m0, n0;
    map_tile(BM, BN, m0, n0);
    const int tid = threadIdx.x;

    f32x4 acc[BM / WR / 16][BN / WC / 16] = {};
    gpipe<BM, BN, WR, WC, TPB, NBUF>(A1, lda1, B1, K1, m0, n0, tid, lds, acc);

    const int lane = tid & 63, wid = tid >> 6;
    const int wr = wid / WC, wc = wid % WC, r16 = lane & 15, rg = lane >> 4;
#pragma unroll
    for (int ni = 0; ni < BN / WC / 16; ++ni) {
        int col = n0 + wc * (BN / WC) + ni * 16 + r16;
        float bv = BIAS ? bias[col] : 0.f;
#pragma unroll
        for (int mi = 0; mi < BM / WR / 16; ++mi) {
#pragma unroll
            for (int r = 0; r < 4; ++r) {
                int row = m0 + wr * (BM / WR) + mi * 16 + rg * 4 + r;
                float v = acc[mi][ni][r] + bv;
                if constexpr (CM == 2) v += bf2f(((const u16*)Ci)[(size_t)row * ldci + col]);
                if constexpr (OUTM == 0) ((float*)Co)[(size_t)row * ldc + col] = v;
                if constexpr (OUTM == 1) ((u16*)Co)[(size_t)row * ldc + col] = f2bf(v);
                if constexpr (OUTM == 2) {
                    int t = row >> 9, b = row & 511;
                    ((float*)Co)[((size_t)b * OT + t) * F_ + col] = v;
                }
                if constexpr (OUTM == 3) {
                    ((float*)Co)[(size_t)row * ldc + col] = v;
                    ((u16*)Co2)[(size_t)row * ldc2 + col] = f2bf(v);
                }
            }
        }
    }
}

// ---------------------------------------------------------------------------
// 8-phase 256x256 GEMM, r18: fragment ds_reads issued BEFORE the phase-align
// barrier (m201 interleave: reads target current tile's buffer, stable all
// 4 quadrant phases; stages write the other buffer -> no hazard; the
// "memory"-clobber barrier pins reads before it, lgkmcnt auto-inserted
// before MFMA use). Counted vmcnt never 0 mid-loop (as r17, verified).
// CM: 0 none, 2 bf16 Cinit. OUTM: 0 fp32, 1 bf16, 2 fp32 (t,b)-remap.
// ---------------------------------------------------------------------------
template <int CM, int BIAS, int OUTM>
__global__ __launch_bounds__(512) void gemm8p(
    const u16* __restrict__ A, long lda, const u16* __restrict__ Bm, int K,
    const void* __restrict__ Ci, long ldci,
    const float* __restrict__ bias, void* __restrict__ Co, long ldc) {
    constexpr int BK = 64;
    __shared__ __align__(16) u16 lds[2 * 512 * BK];  // 128 KiB
    int m0, n0;
    map_tile(256, 256, m0, n0);
    const int tid = threadIdx.x;
    const int lane = tid & 63, wid = tid >> 6;
    const int wm = wid >> 2, wn = wid & 3;
    const int r16 = lane & 15, kg = lane >> 4;
    const int NT = K / BK;

    auto stageA = [&](int T, int half) {
        u16* buf = lds + (T & 1) * 512 * BK;
#pragma unroll
        for (int i = 0; i < 2; ++i) {
            int l = i * 512 + tid;
            int s = l >> 3, sl = l & 7;
            int pr = (s & 63) + ((s >> 6) << 7) + half * 64;
            gl_lds16(A + (size_t)(m0 + pr) * lda + T * BK + ((sl ^ (pr & 7)) * 8),
                     buf + pr * BK + sl * 8);
        }
    };
    auto stageB = [&](int T, int half) {
        u16* buf = lds + (T & 1) * 512 * BK + 256 * BK;
#pragma unroll
        for (int i = 0; i < 2; ++i) {
            int l = i * 512 + tid;
            int s = l >> 3, sl = l & 7;
            int pr = (s & 31) + ((s >> 5) << 6) + half * 32;
            gl_lds16(Bm + (size_t)(n0 + pr) * (size_t)K + T * BK + ((sl ^ (pr & 7)) * 8),
                     buf + pr * BK + sl * 8);
        }
    };

    f32x4 acc[8][4] = {};

    // prologue: tile 0 fully staged + drained (once)
    stageA(0, 0); stageB(0, 0); stageB(0, 1); stageA(0, 1);
    asm volatile("s_waitcnt vmcnt(0)\ns_barrier" ::: "memory");

    for (int t = 0; t < NT; ++t) {
        const u16* Ab = lds + (t & 1) * 512 * BK;
        const u16* Bb = Ab + 256 * BK;
        const bool more = (t + 1 < NT);
#pragma unroll
        for (int q = 0; q < 4; ++q) {
            const int qr = q >> 1, qc = q & 1;
            // (a) fragment ds_reads for quadrant q — BEFORE the barrier;
            // current-tile buffer is stable, latency hides under barrier+stage.
            short8 af[2][4], bf[2][2];
#pragma unroll
            for (int ks = 0; ks < 2; ++ks) {
#pragma unroll
                for (int fi = 0; fi < 4; ++fi) {
                    int row = wm * 128 + qr * 64 + fi * 16 + r16;
                    int s = (ks * 4 + kg) ^ (row & 7);
                    af[ks][fi] = *(const short8*)&Ab[row * BK + s * 8];
                }
#pragma unroll
                for (int fj = 0; fj < 2; ++fj) {
                    int row = wn * 64 + qc * 32 + fj * 16 + r16;
                    int s = (ks * 4 + kg) ^ (row & 7);
                    bf[ks][fj] = *(const short8*)&Bb[row * BK + s * 8];
                }
            }
            // (b) stage half-tile of t+1
            if (more) {
                if (q == 0) stageA(t + 1, 0);
                else if (q == 1) stageB(t + 1, 0);
                else if (q == 2) stageB(t + 1, 1);
                else stageA(t + 1, 1);
            }
            asm volatile("s_barrier" ::: "memory");  // phase align
            __builtin_amdgcn_s_setprio(1);
#pragma unroll
            for (int ks = 0; ks < 2; ++ks)
#pragma unroll
                for (int fi = 0; fi < 4; ++fi)
#pragma unroll
                    for (int fj = 0; fj < 2; ++fj)
                        acc[qr * 4 + fi][qc * 2 + fj] =
                            __builtin_amdgcn_mfma_f32_16x16x32_bf16(
                                af[ks][fi], bf[ks][fj],
                                acc[qr * 4 + fi][qc * 2 + fj], 0, 0, 0);
            __builtin_amdgcn_s_setprio(0);
            if (q == 0) {
                if (more) asm volatile("s_waitcnt vmcnt(4)\ns_barrier" ::: "memory");
                else      asm volatile("s_waitcnt vmcnt(2)\ns_barrier" ::: "memory");
            } else if (q == 1) {
                if (more) asm volatile("s_waitcnt vmcnt(4)\ns_barrier" ::: "memory");
                else      asm volatile("s_waitcnt vmcnt(0)\ns_barrier" ::: "memory");
            } else if (q == 2) {
                asm volatile("s_barrier" ::: "memory");
            } else {
                if (more) asm volatile("s_waitcnt vmcnt(4)\ns_barrier" ::: "memory");
                else      asm volatile("s_barrier" ::: "memory");
            }
        }
    }

    // epilogue
    const int rg = lane >> 4;
#pragma unroll
    for (int ni = 0; ni < 4; ++ni) {
        int col = n0 + wn * 64 + ni * 16 + r16;
        float bv = BIAS ? bias[col] : 0.f;
#pragma unroll
        for (int mi = 0; mi < 8; ++mi) {
#pragma unroll
            for (int r = 0; r < 4; ++r) {
                int row = m0 + wm * 128 + mi * 16 + rg * 4 + r;
                float v = acc[mi][ni][r] + bv;
                if constexpr (CM == 2) v += bf2f(((const u16*)Ci)[(size_t)row * ldci + col]);
                if constexpr (OUTM == 0) ((float*)Co)[(size_t)row * ldc + col] = v;
                if constexpr (OUTM == 1) ((u16*)Co)[(size_t)row * ldc + col] = f2bf(v);
                if constexpr (OUTM == 2) {
                    int tt = row >> 9, b = row & 511;
                    ((float*)Co)[((size_t)b * OT + tt) * F_ + col] = v;
                }
            }
        }
    }
}

// ---------------------------------------------------------------------------
// Fused LSTM step, r15 config (proven 3071/3042): 128x128, 512 thr, grid 256,
// 96 KB LDS, NBUF=3 counted-vmcnt pipeline.
// ---------------------------------------------------------------------------
template <int MODE>
__global__ __launch_bounds__(512) void step128(
    const u16* __restrict__ hin, const u16* __restrict__ Wstep,
    const u16* __restrict__ zx_cur, const float* __restrict__ addv,
    float* __restrict__ c, u16* __restrict__ hout,
    const u16* __restrict__ A2, const u16* __restrict__ B2) {
    __shared__ __align__(16) u16 lds[3 * 256 * 64];  // 96 KB
    float* zt = (float*)lds;
    const int tid = threadIdx.x;
    const int bid = blockIdx.x;
    const int xcd = bid & 7, idx = bid >> 3;
    const int n0 = (xcd * 8 + (idx & 7)) * 128;
    const int m0 = (idx >> 3) * 128;

    f32x4 acc[4][2] = {};
    gpipe<128, 128, 2, 4, 512, 3>(hin, U_, Wstep, U_, m0, n0, tid, lds, acc);
    if constexpr (MODE == 2)
        gpipe<128, 128, 2, 4, 512, 3>(A2, F_, B2, F_, m0, n0, tid, lds, acc);

    {
        const int lane = tid & 63, wid = tid >> 6;
        const int wr = wid >> 2, wc = wid & 3, r16 = lane & 15, rg = lane >> 4;
#pragma unroll
        for (int mi = 0; mi < 4; ++mi)
#pragma unroll
            for (int ni = 0; ni < 2; ++ni)
#pragma unroll
                for (int r = 0; r < 4; ++r)
                    zt[(wr * 64 + mi * 16 + rg * 4 + r) * 132 + wc * 32 + ni * 16 + r16] =
                        acc[mi][ni][r];
    }
    __syncthreads();

    const int row = tid >> 5, ul = tid & 31;
    const int ug = (n0 >> 2) + ul;
#pragma unroll
    for (int j = 0; j < 8; ++j) {
        int rr = j * 16 + row;
        f32x4 zv = *(const f32x4*)&zt[rr * 132 + 4 * ul];
        float zi = zv[0], zf = zv[1], zg = zv[2], zo = zv[3];
        if constexpr (MODE == 0) {
            ushort4 zb = *(const ushort4*)&zx_cur[(size_t)(m0 + rr) * G4 + n0 + 4 * ul];
            zi += bf2f(zb.x); zf += bf2f(zb.y); zg += bf2f(zb.z); zo += bf2f(zb.w);
        } else {
            f32x4 bv = *(const f32x4*)&addv[n0 + 4 * ul];
            zi += bv[0]; zf += bv[1]; zg += bv[2]; zo += bv[3];
        }
        size_t ci = (size_t)(m0 + rr) * U_ + ug;
        float si = 1.f / (1.f + __expf(-zi));
        float sf = 1.f / (1.f + __expf(-zf));
        float so = 1.f / (1.f + __expf(-zo));
        float cc = sf * c[ci] + si * tanhf(zg);
        c[ci] = cc;
        hout[ci] = f2bf(so * tanhf(cc));
    }
}

// ---------------------------------------------------------------------------
extern "C" void kernel_launch(void* const* d_in, const int* in_sizes, int n_in,
                              void* d_out, int out_size, void* d_ws, size_t ws_size,
                              hipStream_t stream) {
    const float* x = (const float*)d_in[0];
    const float* Wk = (const float*)d_in[1];
    const float* Wr = (const float*)d_in[2];
    const float* bias = (const float*)d_in[3];
    const float* Wd = (const float*)d_in[4];
    const float* bd = (const float*)d_in[5];
    float* out = (float*)d_out;

    u16* xbf = (u16*)d_out;

    auto pad = [](size_t s) { return (s + 255) & ~(size_t)255; };
    const size_t szW4 = (size_t)G4 * U_ * 2;
    const size_t szDT = (size_t)U_ * F_ * 2;
    const size_t szB4 = (size_t)G4 * 4;
    const size_t szH = (size_t)OT * B_ * U_ * 2;
    const size_t szHP = (size_t)B_ * U_ * 2;
    const size_t szC = (size_t)B_ * U_ * 4;
    const size_t szZX1 = (size_t)B_ * G4 * 2;
    const size_t SLOT = (size_t)B_ * U_;

    const size_t needMain = pad(szW4) * 3 + pad(szDT) * 2 + pad(szB4) * 2 +
                            pad(szH) + pad(szHP) * 2 + pad(szC) + pad(szZX1);
    const int path = ws_size >= needMain ? 1 : 0;

    char* p = (char*)d_ws;
    auto alloc = [&](size_t bytes) { void* r = p; p += (bytes + 255) & ~(size_t)255; return r; };

    dim3 tb32(32, 8);

    if (path == 1) {
        u16* W4kT = (u16*)alloc(szW4);
        u16* W4rT = (u16*)alloc(szW4);
        u16* W4cT = (u16*)alloc(szW4);
        u16* dT = (u16*)alloc(szDT);
        u16* dbf = (u16*)alloc(szDT);
        float* bias4 = (float*)alloc(szB4);
        float* bc4 = (float*)alloc(szB4);
        u16* H = (u16*)alloc(szH);
        u16* hp0 = (u16*)alloc(szHP);
        u16* hp1 = (u16*)alloc(szHP);
        float* c = (float*)alloc(szC);

        size_t avail = ws_size - (size_t)(p - (char*)d_ws);
        int chunk = (int)(avail / szZX1);
        if (chunk > T_) chunk = T_;
        u16* ZX = (u16*)alloc((size_t)chunk * szZX1);

        cvt_x_tmajor<<<(B_ * T_ * F_ / 4 + 255) / 256, 256, 0, stream>>>(x, xbf);
        transpose_f32_bf16<1><<<dim3(G4 / 32, F_ / 32), tb32, 0, stream>>>(Wk, W4kT, F_, G4);
        transpose_f32_bf16<1><<<dim3(G4 / 32, U_ / 32), tb32, 0, stream>>>(Wr, W4rT, U_, G4);
        transpose_f32_bf16<0><<<dim3(F_ / 32, U_ / 32), tb32, 0, stream>>>(Wd, dT, U_, F_);
        cvt_bf16<<<(U_ * F_ / 4 + 255) / 256, 256, 0, stream>>>(Wd, dbf, (long)U_ * F_);
        make_bias4<<<G4 / 256, 256, 0, stream>>>(bias, bias4);
        bcomb_k<<<G4 / 4, 256, 0, stream>>>(W4kT, bd, bias4, bc4);

        // W4cT = W4rT + W4kT @ Wd^T  (8-phase)
        gemm8p<2, 0, 1><<<dim3(U_ / 256, G4 / 256), 512, 0, stream>>>(
            W4kT, U_, dbf, F_, W4rT, U_, nullptr, W4cT, U_);

        hipMemsetAsync(c, 0, szC, stream);
        hipMemsetAsync(hp0, 0, szHP, stream);

        for (int t0 = 0; t0 < T_; t0 += chunk) {
            int nc = chunk < T_ - t0 ? chunk : T_ - t0;
            // ZX[tt] = x_tt @ W4kT + bias4  (bf16) — 8-phase
            gemm8p<0, 1, 1><<<dim3(G4 / 256, nc * B_ / 256), 512, 0, stream>>>(
                xbf + (size_t)t0 * B_ * F_, F_, W4kT, F_, nullptr, 0, bias4, ZX, G4);
            for (int t = t0; t < t0 + nc; ++t) {
                const u16* hin = (t & 1) ? hp1 : hp0;
                u16* hout = (t == T_ - 1) ? H : ((t & 1) ? hp0 : hp1);
                step128<0><<<256, 512, 0, stream>>>(
                    hin, W4rT, ZX + (size_t)(t - t0) * B_ * G4, nullptr,
                    c, hout, nullptr, nullptr);
            }
        }
        for (int t = 1; t < OT; ++t) {
            step128<1><<<256, 512, 0, stream>>>(
                H + (size_t)(t - 1) * SLOT, W4cT, nullptr, bc4,
                c, H + (size_t)t * SLOT, nullptr, nullptr);
        }
        // out[b][t][f] = H[t][b] @ Wd + bd  (8-phase, (t,b)-remap)
        gemm8p<0, 1, 2><<<dim3(F_ / 256, OT * B_ / 256), 512, 0, stream>>>(
            H, U_, dT, U_, nullptr, 0, bd, out, F_);
    } else {
        // Fallback (~82 MB)
        u16* W4kT = (u16*)alloc(szW4);
        u16* W4rT = (u16*)alloc(szW4);
        u16* dT = (u16*)alloc(szDT);
        float* bias4 = (float*)alloc(szB4);
        u16* hp0 = (u16*)alloc(szHP);
        u16* hp1 = (u16*)alloc(szHP);
        u16* pred = (u16*)alloc(szHP);
        float* c = (float*)alloc(szC);

        cvt_x_tmajor<<<(B_ * T_ * F_ / 4 + 255) / 256, 256, 0, stream>>>(x, xbf);
        transpose_f32_bf16<1><<<dim3(G4 / 32, F_ / 32), tb32, 0, stream>>>(Wk, W4kT, F_, G4);
        transpose_f32_bf16<1><<<dim3(G4 / 32, U_ / 32), tb32, 0, stream>>>(Wr, W4rT, U_, G4);
        transpose_f32_bf16<0><<<dim3(F_ / 32, U_ / 32), tb32, 0, stream>>>(Wd, dT, U_, F_);
        make_bias4<<<G4 / 256, 256, 0, stream>>>(bias, bias4);
        hipMemsetAsync(c, 0, szC, stream);
        hipMemsetAsync(hp0, 0, szHP, stream);

        u16* hin = hp0;
        u16* hout = hp1;
        for (int t = 0; t < T_; ++t) {
            step128<2><<<256, 512, 0, stream>>>(
                hin, W4rT, nullptr, bias4, c, hout,
                xbf + (size_t)t * B_ * F_, W4kT);
            u16* tmp = hin; hin = hout; hout = tmp;
        }
        gemm3<64, 128, 2, 2, 256, 3, 0, 1, 3><<<dim3(F_ / 128, B_ / 64), 256, 0, stream>>>(
            hin, U_, dT, U_, nullptr, 0, bd, out, (long)OT * F_, pred, U_);
        for (int t = 1; t < OT; ++t) {
            step128<2><<<256, 512, 0, stream>>>(
                hin, W4rT, nullptr, bias4, c, hout, pred, W4kT);
            u16* tmp = hin; hin = hout; hout = tmp;
            gemm3<64, 128, 2, 2, 256, 3, 0, 1, 3><<<dim3(F_ / 128, B_ / 64), 256, 0, stream>>>(
                hin, U_, dT, U_, nullptr, 0, bd, out + (size_t)t * F_, (long)OT * F_, pred, U_);
        }
    }
}

// Round 19
// 3033.486 us; speedup vs baseline: 1.0384x; 1.0384x over previous
//
#include <hip/hip_runtime.h>
#include <hip/hip_bf16.h>
#include <cstddef>
#include <cstdint>

typedef __attribute__((ext_vector_type(8))) short short8;
typedef __attribute__((ext_vector_type(4))) float f32x4;
typedef unsigned short u16;
typedef unsigned int u32;

#define B_ 512
#define T_ 48
#define F_ 2048
#define U_ 2048
#define G4 8192
#define OT 24

__device__ __forceinline__ u16 f2bf(float f) {
    __hip_bfloat16 b = __float2bfloat16(f);
    return *reinterpret_cast<u16*>(&b);
}
__device__ __forceinline__ float bf2f(u16 v) {
    union { u32 u; float f; } c;
    c.u = ((u32)v) << 16;
    return c.f;
}

__device__ __forceinline__ void gl_lds16(const void* g, void* l) {
    __builtin_amdgcn_global_load_lds(
        (const __attribute__((address_space(1))) void*)g,
        (__attribute__((address_space(3))) void*)l, 16, 0, 0);
}

// ---------------------------------------------------------------------------
// XCD/L2-aware tile mapping (proven r6/r7).
// ---------------------------------------------------------------------------
__device__ __forceinline__ void map_tile(int BM, int BN, int& m0, int& n0) {
    const int gx = gridDim.x, gy = gridDim.y;
    int lin = blockIdx.y * gx + blockIdx.x;
    const int nwg = gx * gy;
    const int sn = gx >> 3;
    const int EN = (sn >= 4) ? 4 : sn;
    const int EM = 4;
    bool ok = ((gx & 7) == 0) && ((gy & 3) == 0) && (sn < 4 || (sn & 3) == 0);
    if (ok) {
        int xcd = lin & 7, idx = lin >> 3;
        int epw = EM * EN;
        int e = idx / epw, r = idx % epw;
        int meb = gy / EM;
        int ne = e / meb, me = e % meb;
        int mi = r % EM, nli = r / EM;
        m0 = (me * EM + mi) * BM;
        n0 = (xcd * sn + ne * EN + nli) * BN;
    } else {
        if ((nwg & 7) == 0) {
            int q = nwg >> 3;
            lin = (lin & 7) * q + (lin >> 3);
        }
        m0 = (lin / gx) * BM;
        n0 = (lin % gx) * BN;
    }
}

// ---------------------------------------------------------------------------
// fp32 [R][C] -> bf16 [C][R]; ILV=1 -> gate-interleaved rows n'=(u<<2)|g.
// ---------------------------------------------------------------------------
template <int ILV>
__global__ void transpose_f32_bf16(const float* __restrict__ in,
                                   u16* __restrict__ out, int R, int C) {
    __shared__ float tile[32][33];
    int bx = blockIdx.x * 32;
    int by = blockIdx.y * 32;
    int tx = threadIdx.x, ty = threadIdx.y;
#pragma unroll
    for (int j = 0; j < 32; j += 8)
        tile[ty + j][tx] = in[(size_t)(by + ty + j) * C + bx + tx];
    __syncthreads();
#pragma unroll
    for (int j = 0; j < 32; j += 8) {
        int cidx = bx + ty + j;
        int orow = ILV ? (((cidx & 2047) << 2) | (cidx >> 11)) : cidx;
        out[(size_t)orow * R + by + tx] = f2bf(tile[tx][ty + j]);
    }
}

__global__ void cvt_bf16(const float* __restrict__ in, u16* __restrict__ out, long n) {
    long i = ((long)blockIdx.x * blockDim.x + threadIdx.x) * 4;
    if (i >= n) return;
    f32x4 v = *(const f32x4*)(in + i);
    ushort4 o;
    o.x = f2bf(v[0]); o.y = f2bf(v[1]); o.z = f2bf(v[2]); o.w = f2bf(v[3]);
    *(ushort4*)(out + i) = o;
}

// x [b][t][f] fp32 -> xbf [t][b][f] bf16
__global__ void cvt_x_tmajor(const float* __restrict__ x, u16* __restrict__ xbf) {
    long i = ((long)blockIdx.x * blockDim.x + threadIdx.x) * 4;
    int f = (int)(i & (F_ - 1));
    long bt = i >> 11;
    int t = (int)(bt % T_);
    int b = (int)(bt / T_);
    f32x4 v = *(const f32x4*)(x + i);
    ushort4 o;
    o.x = f2bf(v[0]); o.y = f2bf(v[1]); o.z = f2bf(v[2]); o.w = f2bf(v[3]);
    *(ushort4*)(xbf + ((size_t)t * B_ + b) * F_ + f) = o;
}

__global__ void make_bias4(const float* __restrict__ bias, float* __restrict__ b4) {
    int n = blockIdx.x * 256 + threadIdx.x;
    int g = n & 3, u = n >> 2;
    b4[n] = bias[g * 2048 + u];
}

__global__ void bcomb_k(const u16* __restrict__ W4kT, const float* __restrict__ bd,
                        const float* __restrict__ bias4, float* __restrict__ bc) {
    int lane = threadIdx.x & 63, wid = threadIdx.x >> 6;
    int n = blockIdx.x * 4 + wid;
    const u16* row = W4kT + (size_t)n * U_;
    float s = 0.f;
    for (int j0 = lane * 8; j0 < U_; j0 += 512) {
        short8 v = *(const short8*)&row[j0];
#pragma unroll
        for (int e = 0; e < 8; ++e) s += bd[j0 + e] * bf2f((u16)v[e]);
    }
#pragma unroll
    for (int o = 32; o; o >>= 1) s += __shfl_down(s, o);
    if (lane == 0) bc[n] = bias4[n] + s;
}

// ---------------------------------------------------------------------------
// Counted-vmcnt GEMM pipeline, generalized over BK (S = BK/8 slots/row;
// stage swizzle sl^(r&(S-1)) matches read (ks*4+kg)^(row&(S-1)) — same
// involution both sides; S=8 reduces to the r7-proven code).
// NBUF=3: vmcnt 2*LPS/LPS/0. NBUF=2: vmcnt LPS/0.
// ---------------------------------------------------------------------------
template <int BM, int BN, int WR, int WC, int TPB, int NBUF, int BK>
__device__ __forceinline__ void gpipe(const u16* __restrict__ A, long lda,
                                      const u16* __restrict__ B, int K,
                                      int m0, int n0, int tid, u16* lds,
                                      f32x4 (&acc)[BM / WR / 16][BN / WC / 16]) {
    constexpr int S = BK / 8;
    constexpr int MF = BM / WR / 16, NF = BN / WC / 16;
    constexpr int TILE = (BM + BN) * BK;
    constexpr int LA = BM * BK / (TPB * 8);
    constexpr int LB = BN * BK / (TPB * 8);
    constexpr int LPS = LA + LB;
    static_assert((NBUF == 3 && (LPS == 4 || LPS == 6)) ||
                  (NBUF == 2 && (LPS == 6 || LPS == 8)), "vmcnt table");
    const int lane = tid & 63, wid = tid >> 6;
    const int wr = wid / WC, wc = wid % WC;
    const int r16 = lane & 15, kg = lane >> 4;
    const int kpar = wid & 1;
    const int NT = K / BK;

    auto stage = [&](int t) {
        if (t >= NT) return;
        const u16* Abase = A + (size_t)m0 * lda + (size_t)t * BK;
        const u16* Bbase = B + (size_t)n0 * (size_t)K + (size_t)t * BK;
        u16* dst = lds + (t % NBUF) * TILE;
#pragma unroll
        for (int i = 0; i < LA; ++i) {
            int idx = i * TPB + tid;
            int r = idx / S, sl = idx % S;
            gl_lds16(Abase + (size_t)r * lda + ((sl ^ (r & (S - 1))) * 8), dst + idx * 8);
        }
        u16* dstB = dst + BM * BK;
#pragma unroll
        for (int i = 0; i < LB; ++i) {
            int idx = i * TPB + tid;
            int r = idx / S, sl = idx % S;
            gl_lds16(Bbase + (size_t)r * (size_t)K + ((sl ^ (r & (S - 1))) * 8), dstB + idx * 8);
        }
    };
    auto compute = [&](int t) {
        const u16* Ab = lds + (t % NBUF) * TILE;
        const u16* Bb = Ab + BM * BK;
        __builtin_amdgcn_s_setprio(1);
#pragma unroll
        for (int ks2 = 0; ks2 < BK / 32; ++ks2) {
            const int ks = ks2 ^ kpar;  // wave parity stagger (bijective)
            short8 af[MF], bf[NF];
#pragma unroll
            for (int mi = 0; mi < MF; ++mi) {
                int row = wr * (BM / WR) + mi * 16 + r16;
                int s = (ks * 4 + kg) ^ (row & (S - 1));
                af[mi] = *(const short8*)&Ab[row * BK + s * 8];
            }
#pragma unroll
            for (int ni = 0; ni < NF; ++ni) {
                int row = wc * (BN / WC) + ni * 16 + r16;
                int s = (ks * 4 + kg) ^ (row & (S - 1));
                bf[ni] = *(const short8*)&Bb[row * BK + s * 8];
            }
#pragma unroll
            for (int mi = 0; mi < MF; ++mi)
#pragma unroll
                for (int ni = 0; ni < NF; ++ni)
                    acc[mi][ni] = __builtin_amdgcn_mfma_f32_16x16x32_bf16(
                        af[mi], bf[ni], acc[mi][ni], 0, 0, 0);
        }
        __builtin_amdgcn_s_setprio(0);
    };

    if constexpr (NBUF == 3) {
        stage(0);
        stage(1);
        for (int t = 0; t < NT; ++t) {
            stage(t + 2);
            if (t + 2 < NT) {
                if constexpr (LPS == 6)
                    asm volatile("s_waitcnt vmcnt(12)\ns_barrier" ::: "memory");
                else
                    asm volatile("s_waitcnt vmcnt(8)\ns_barrier" ::: "memory");
            } else if (t + 1 < NT) {
                if constexpr (LPS == 6)
                    asm volatile("s_waitcnt vmcnt(6)\ns_barrier" ::: "memory");
                else
                    asm volatile("s_waitcnt vmcnt(4)\ns_barrier" ::: "memory");
            } else {
                asm volatile("s_waitcnt vmcnt(0)\ns_barrier" ::: "memory");
            }
            compute(t);
            asm volatile("s_barrier" ::: "memory");
        }
    } else {
        stage(0);
        for (int t = 0; t < NT; ++t) {
            stage(t + 1);
            if (t + 1 < NT) {
                if constexpr (LPS == 8)
                    asm volatile("s_waitcnt vmcnt(8)\ns_barrier" ::: "memory");
                else
                    asm volatile("s_waitcnt vmcnt(6)\ns_barrier" ::: "memory");
            } else {
                asm volatile("s_waitcnt vmcnt(0)\ns_barrier" ::: "memory");
            }
            compute(t);
            asm volatile("s_barrier" ::: "memory");
        }
    }
}

// CM: 0 none, 2 bf16 Cinit. OUTM: 0 fp32, 1 bf16, 2 fp32 (t,b)-remap,
// 3 fp32 (ldc) + bf16 secondary (ldc2).
template <int BM, int BN, int WR, int WC, int TPB, int NBUF, int CM, int BIAS, int OUTM>
__global__ __launch_bounds__(TPB) void gemm3(
    const u16* __restrict__ A1, long lda1, const u16* __restrict__ B1, int K1,
    const void* __restrict__ Ci, long ldci, const float* __restrict__ bias,
    void* __restrict__ Co, long ldc, void* __restrict__ Co2, long ldc2) {
    __shared__ __align__(16) u16 lds[NBUF * (BM + BN) * 64];
    int m0, n0;
    map_tile(BM, BN, m0, n0);
    const int tid = threadIdx.x;

    f32x4 acc[BM / WR / 16][BN / WC / 16] = {};
    gpipe<BM, BN, WR, WC, TPB, NBUF, 64>(A1, lda1, B1, K1, m0, n0, tid, lds, acc);

    const int lane = tid & 63, wid = tid >> 6;
    const int wr = wid / WC, wc = wid % WC, r16 = lane & 15, rg = lane >> 4;
#pragma unroll
    for (int ni = 0; ni < BN / WC / 16; ++ni) {
        int col = n0 + wc * (BN / WC) + ni * 16 + r16;
        float bv = BIAS ? bias[col] : 0.f;
#pragma unroll
        for (int mi = 0; mi < BM / WR / 16; ++mi) {
#pragma unroll
            for (int r = 0; r < 4; ++r) {
                int row = m0 + wr * (BM / WR) + mi * 16 + rg * 4 + r;
                float v = acc[mi][ni][r] + bv;
                if constexpr (CM == 2) v += bf2f(((const u16*)Ci)[(size_t)row * ldci + col]);
                if constexpr (OUTM == 0) ((float*)Co)[(size_t)row * ldc + col] = v;
                if constexpr (OUTM == 1) ((u16*)Co)[(size_t)row * ldc + col] = f2bf(v);
                if constexpr (OUTM == 2) {
                    int t = row >> 9, b = row & 511;
                    ((float*)Co)[((size_t)b * OT + t) * F_ + col] = v;
                }
                if constexpr (OUTM == 3) {
                    ((float*)Co)[(size_t)row * ldc + col] = v;
                    ((u16*)Co2)[(size_t)row * ldc2 + col] = f2bf(v);
                }
            }
        }
    }
}

// ---------------------------------------------------------------------------
// 8-phase 256x256 GEMM (r17 form — reads AFTER the phase barrier; proven
// 903 µs @ ZX, VGPR 92). Counted vmcnt never 0 mid-loop.
// ---------------------------------------------------------------------------
template <int BIAS, int OUTM>
__global__ __launch_bounds__(512) void gemm8p(
    const u16* __restrict__ A, long lda, const u16* __restrict__ Bm, int K,
    const float* __restrict__ bias, void* __restrict__ Co, long ldc) {
    constexpr int BK = 64;
    __shared__ __align__(16) u16 lds[2 * 512 * BK];  // 128 KiB
    int m0, n0;
    map_tile(256, 256, m0, n0);
    const int tid = threadIdx.x;
    const int lane = tid & 63, wid = tid >> 6;
    const int wm = wid >> 2, wn = wid & 3;
    const int r16 = lane & 15, kg = lane >> 4;
    const int NT = K / BK;

    auto stageA = [&](int T, int half) {
        u16* buf = lds + (T & 1) * 512 * BK;
#pragma unroll
        for (int i = 0; i < 2; ++i) {
            int l = i * 512 + tid;
            int s = l >> 3, sl = l & 7;
            int pr = (s & 63) + ((s >> 6) << 7) + half * 64;
            gl_lds16(A + (size_t)(m0 + pr) * lda + T * BK + ((sl ^ (pr & 7)) * 8),
                     buf + pr * BK + sl * 8);
        }
    };
    auto stageB = [&](int T, int half) {
        u16* buf = lds + (T & 1) * 512 * BK + 256 * BK;
#pragma unroll
        for (int i = 0; i < 2; ++i) {
            int l = i * 512 + tid;
            int s = l >> 3, sl = l & 7;
            int pr = (s & 31) + ((s >> 5) << 6) + half * 32;
            gl_lds16(Bm + (size_t)(n0 + pr) * (size_t)K + T * BK + ((sl ^ (pr & 7)) * 8),
                     buf + pr * BK + sl * 8);
        }
    };

    f32x4 acc[8][4] = {};

    stageA(0, 0); stageB(0, 0); stageB(0, 1); stageA(0, 1);
    asm volatile("s_waitcnt vmcnt(0)\ns_barrier" ::: "memory");

    for (int t = 0; t < NT; ++t) {
        const u16* Ab = lds + (t & 1) * 512 * BK;
        const u16* Bb = Ab + 256 * BK;
        const bool more = (t + 1 < NT);
#pragma unroll
        for (int q = 0; q < 4; ++q) {
            const int qr = q >> 1, qc = q & 1;
            if (more) {
                if (q == 0) stageA(t + 1, 0);
                else if (q == 1) stageB(t + 1, 0);
                else if (q == 2) stageB(t + 1, 1);
                else stageA(t + 1, 1);
            }
            asm volatile("s_barrier" ::: "memory");
            __builtin_amdgcn_s_setprio(1);
#pragma unroll
            for (int ks = 0; ks < 2; ++ks) {
                short8 af[4], bf[2];
#pragma unroll
                for (int fi = 0; fi < 4; ++fi) {
                    int row = wm * 128 + qr * 64 + fi * 16 + r16;
                    int s = (ks * 4 + kg) ^ (row & 7);
                    af[fi] = *(const short8*)&Ab[row * BK + s * 8];
                }
#pragma unroll
                for (int fj = 0; fj < 2; ++fj) {
                    int row = wn * 64 + qc * 32 + fj * 16 + r16;
                    int s = (ks * 4 + kg) ^ (row & 7);
                    bf[fj] = *(const short8*)&Bb[row * BK + s * 8];
                }
#pragma unroll
                for (int fi = 0; fi < 4; ++fi)
#pragma unroll
                    for (int fj = 0; fj < 2; ++fj)
                        acc[qr * 4 + fi][qc * 2 + fj] =
                            __builtin_amdgcn_mfma_f32_16x16x32_bf16(
                                af[fi], bf[fj], acc[qr * 4 + fi][qc * 2 + fj], 0, 0, 0);
            }
            __builtin_amdgcn_s_setprio(0);
            if (q == 0) {
                if (more) asm volatile("s_waitcnt vmcnt(4)\ns_barrier" ::: "memory");
                else      asm volatile("s_waitcnt vmcnt(2)\ns_barrier" ::: "memory");
            } else if (q == 1) {
                if (more) asm volatile("s_waitcnt vmcnt(4)\ns_barrier" ::: "memory");
                else      asm volatile("s_waitcnt vmcnt(0)\ns_barrier" ::: "memory");
            } else if (q == 2) {
                asm volatile("s_barrier" ::: "memory");
            } else {
                if (more) asm volatile("s_waitcnt vmcnt(4)\ns_barrier" ::: "memory");
                else      asm volatile("s_barrier" ::: "memory");
            }
        }
    }

    const int rg = lane >> 4;
#pragma unroll
    for (int ni = 0; ni < 4; ++ni) {
        int col = n0 + wn * 64 + ni * 16 + r16;
        float bv = BIAS ? bias[col] : 0.f;
#pragma unroll
        for (int mi = 0; mi < 8; ++mi) {
#pragma unroll
            for (int r = 0; r < 4; ++r) {
                int row = m0 + wm * 128 + mi * 16 + rg * 4 + r;
                float v = acc[mi][ni][r] + bv;
                if constexpr (OUTM == 0) ((float*)Co)[(size_t)row * ldc + col] = v;
                if constexpr (OUTM == 1) ((u16*)Co)[(size_t)row * ldc + col] = f2bf(v);
            }
        }
    }
}

// ---------------------------------------------------------------------------
// Fused LSTM step, r19: 128x128, 512 thr (8 waves 2x4), grid 256, BK=128
// NBUF=2 (128 KB LDS, 1 block/CU = 8 waves/CU — same occupancy as r15's
// 96 KB; identical prefetch bytes: 1 full tile ahead vs 2 half-tiles) —
// HALF the barrier crossings (NT 32->16).
// MODE 0: warmup (z += zx_cur). MODE 1: decode (z += bc4, W=Wcomb).
// MODE 2: fallback dual GEMM.
// ---------------------------------------------------------------------------
template <int MODE>
__global__ __launch_bounds__(512) void step128(
    const u16* __restrict__ hin, const u16* __restrict__ Wstep,
    const u16* __restrict__ zx_cur, const float* __restrict__ addv,
    float* __restrict__ c, u16* __restrict__ hout,
    const u16* __restrict__ A2, const u16* __restrict__ B2) {
    __shared__ __align__(16) u16 lds[2 * 256 * 128];  // 128 KB
    float* zt = (float*)lds;  // 128 x 132 fp32 alias (67.6 KB)
    const int tid = threadIdx.x;
    const int bid = blockIdx.x;
    const int xcd = bid & 7, idx = bid >> 3;
    const int n0 = (xcd * 8 + (idx & 7)) * 128;
    const int m0 = (idx >> 3) * 128;

    f32x4 acc[4][2] = {};
    gpipe<128, 128, 2, 4, 512, 2, 128>(hin, U_, Wstep, U_, m0, n0, tid, lds, acc);
    if constexpr (MODE == 2)
        gpipe<128, 128, 2, 4, 512, 2, 128>(A2, F_, B2, F_, m0, n0, tid, lds, acc);

    __syncthreads();
    {
        const int lane = tid & 63, wid = tid >> 6;
        const int wr = wid >> 2, wc = wid & 3, r16 = lane & 15, rg = lane >> 4;
#pragma unroll
        for (int mi = 0; mi < 4; ++mi)
#pragma unroll
            for (int ni = 0; ni < 2; ++ni)
#pragma unroll
                for (int r = 0; r < 4; ++r)
                    zt[(wr * 64 + mi * 16 + rg * 4 + r) * 132 + wc * 32 + ni * 16 + r16] =
                        acc[mi][ni][r];
    }
    __syncthreads();

    const int row = tid >> 5, ul = tid & 31;
    const int ug = (n0 >> 2) + ul;
#pragma unroll
    for (int j = 0; j < 8; ++j) {
        int rr = j * 16 + row;
        f32x4 zv = *(const f32x4*)&zt[rr * 132 + 4 * ul];
        float zi = zv[0], zf = zv[1], zg = zv[2], zo = zv[3];
        if constexpr (MODE == 0) {
            ushort4 zb = *(const ushort4*)&zx_cur[(size_t)(m0 + rr) * G4 + n0 + 4 * ul];
            zi += bf2f(zb.x); zf += bf2f(zb.y); zg += bf2f(zb.z); zo += bf2f(zb.w);
        } else {
            f32x4 bv = *(const f32x4*)&addv[n0 + 4 * ul];
            zi += bv[0]; zf += bv[1]; zg += bv[2]; zo += bv[3];
        }
        size_t ci = (size_t)(m0 + rr) * U_ + ug;
        float si = 1.f / (1.f + __expf(-zi));
        float sf = 1.f / (1.f + __expf(-zf));
        float so = 1.f / (1.f + __expf(-zo));
        float cc = sf * c[ci] + si * tanhf(zg);
        c[ci] = cc;
        hout[ci] = f2bf(so * tanhf(cc));
    }
}

// ---------------------------------------------------------------------------
extern "C" void kernel_launch(void* const* d_in, const int* in_sizes, int n_in,
                              void* d_out, int out_size, void* d_ws, size_t ws_size,
                              hipStream_t stream) {
    const float* x = (const float*)d_in[0];
    const float* Wk = (const float*)d_in[1];
    const float* Wr = (const float*)d_in[2];
    const float* bias = (const float*)d_in[3];
    const float* Wd = (const float*)d_in[4];
    const float* bd = (const float*)d_in[5];
    float* out = (float*)d_out;

    u16* xbf = (u16*)d_out;

    auto pad = [](size_t s) { return (s + 255) & ~(size_t)255; };
    const size_t szW4 = (size_t)G4 * U_ * 2;
    const size_t szDT = (size_t)U_ * F_ * 2;
    const size_t szB4 = (size_t)G4 * 4;
    const size_t szH = (size_t)OT * B_ * U_ * 2;
    const size_t szHP = (size_t)B_ * U_ * 2;
    const size_t szC = (size_t)B_ * U_ * 4;
    const size_t szZX1 = (size_t)B_ * G4 * 2;
    const size_t SLOT = (size_t)B_ * U_;

    const size_t needMain = pad(szW4) * 3 + pad(szDT) * 2 + pad(szB4) * 2 +
                            pad(szH) + pad(szHP) * 2 + pad(szC) + pad(szZX1);
    const int path = ws_size >= needMain ? 1 : 0;

    char* p = (char*)d_ws;
    auto alloc = [&](size_t bytes) { void* r = p; p += (bytes + 255) & ~(size_t)255; return r; };

    dim3 tb32(32, 8);

    if (path == 1) {
        u16* W4kT = (u16*)alloc(szW4);
        u16* W4rT = (u16*)alloc(szW4);
        u16* W4cT = (u16*)alloc(szW4);
        u16* dT = (u16*)alloc(szDT);
        u16* dbf = (u16*)alloc(szDT);
        float* bias4 = (float*)alloc(szB4);
        float* bc4 = (float*)alloc(szB4);
        u16* H = (u16*)alloc(szH);
        u16* hp0 = (u16*)alloc(szHP);
        u16* hp1 = (u16*)alloc(szHP);
        float* c = (float*)alloc(szC);

        size_t avail = ws_size - (size_t)(p - (char*)d_ws);
        int chunk = (int)(avail / szZX1);
        if (chunk > T_) chunk = T_;
        u16* ZX = (u16*)alloc((size_t)chunk * szZX1);

        cvt_x_tmajor<<<(B_ * T_ * F_ / 4 + 255) / 256, 256, 0, stream>>>(x, xbf);
        transpose_f32_bf16<1><<<dim3(G4 / 32, F_ / 32), tb32, 0, stream>>>(Wk, W4kT, F_, G4);
        transpose_f32_bf16<1><<<dim3(G4 / 32, U_ / 32), tb32, 0, stream>>>(Wr, W4rT, U_, G4);
        transpose_f32_bf16<0><<<dim3(F_ / 32, U_ / 32), tb32, 0, stream>>>(Wd, dT, U_, F_);
        cvt_bf16<<<(U_ * F_ / 4 + 255) / 256, 256, 0, stream>>>(Wd, dbf, (long)U_ * F_);
        make_bias4<<<G4 / 256, 256, 0, stream>>>(bias, bias4);
        bcomb_k<<<G4 / 4, 256, 0, stream>>>(W4kT, bd, bias4, bc4);

        // W4cT = W4rT + W4kT @ Wd^T  (256² coarse, proven)
        gemm3<256, 256, 2, 4, 512, 2, 2, 0, 1><<<dim3(U_ / 256, G4 / 256), 512, 0, stream>>>(
            W4kT, U_, dbf, F_, W4rT, U_, nullptr, W4cT, U_, nullptr, 0);

        hipMemsetAsync(c, 0, szC, stream);
        hipMemsetAsync(hp0, 0, szHP, stream);

        for (int t0 = 0; t0 < T_; t0 += chunk) {
            int nc = chunk < T_ - t0 ? chunk : T_ - t0;
            // ZX[tt] = x_tt @ W4kT + bias4  (bf16) — 8-phase (r17 form)
            gemm8p<1, 1><<<dim3(G4 / 256, nc * B_ / 256), 512, 0, stream>>>(
                xbf + (size_t)t0 * B_ * F_, F_, W4kT, F_, bias4, ZX, G4);
            for (int t = t0; t < t0 + nc; ++t) {
                const u16* hin = (t & 1) ? hp1 : hp0;
                u16* hout = (t == T_ - 1) ? H : ((t & 1) ? hp0 : hp1);
                step128<0><<<256, 512, 0, stream>>>(
                    hin, W4rT, ZX + (size_t)(t - t0) * B_ * G4, nullptr,
                    c, hout, nullptr, nullptr);
            }
        }
        for (int t = 1; t < OT; ++t) {
            step128<1><<<256, 512, 0, stream>>>(
                H + (size_t)(t - 1) * SLOT, W4cT, nullptr, bc4,
                c, H + (size_t)t * SLOT, nullptr, nullptr);
        }
        // out[b][t][f] = H[t][b] @ Wd + bd  (256² coarse)
        gemm3<256, 256, 2, 4, 512, 2, 0, 1, 2><<<dim3(F_ / 256, OT * B_ / 256), 512, 0, stream>>>(
            H, U_, dT, U_, nullptr, 0, bd, out, F_, nullptr, 0);
    } else {
        // Fallback (~82 MB)
        u16* W4kT = (u16*)alloc(szW4);
        u16* W4rT = (u16*)alloc(szW4);
        u16* dT = (u16*)alloc(szDT);
        float* bias4 = (float*)alloc(szB4);
        u16* hp0 = (u16*)alloc(szHP);
        u16* hp1 = (u16*)alloc(szHP);
        u16* pred = (u16*)alloc(szHP);
        float* c = (float*)alloc(szC);

        cvt_x_tmajor<<<(B_ * T_ * F_ / 4 + 255) / 256, 256, 0, stream>>>(x, xbf);
        transpose_f32_bf16<1><<<dim3(G4 / 32, F_ / 32), tb32, 0, stream>>>(Wk, W4kT, F_, G4);
        transpose_f32_bf16<1><<<dim3(G4 / 32, U_ / 32), tb32, 0, stream>>>(Wr, W4rT, U_, G4);
        transpose_f32_bf16<0><<<dim3(F_ / 32, U_ / 32), tb32, 0, stream>>>(Wd, dT, U_, F_);
        make_bias4<<<G4 / 256, 256, 0, stream>>>(bias, bias4);
        hipMemsetAsync(c, 0, szC, stream);
        hipMemsetAsync(hp0, 0, szHP, stream);

        u16* hin = hp0;
        u16* hout = hp1;
        for (int t = 0; t < T_; ++t) {
            step128<2><<<256, 512, 0, stream>>>(
                hin, W4rT, nullptr, bias4, c, hout,
                xbf + (size_t)t * B_ * F_, W4kT);
            u16* tmp = hin; hin = hout; hout = tmp;
        }
        gemm3<64, 128, 2, 2, 256, 3, 0, 1, 3><<<dim3(F_ / 128, B_ / 64), 256, 0, stream>>>(
            hin, U_, dT, U_, nullptr, 0, bd, out, (long)OT * F_, pred, U_);
        for (int t = 1; t < OT; ++t) {
            step128<2><<<256, 512, 0, stream>>>(
                hin, W4rT, nullptr, bias4, c, hout, pred, W4kT);
            u16* tmp = hin; hin = hout; hout = tmp;
            gemm3<64, 128, 2, 2, 256, 3, 0, 1, 3><<<dim3(F_ / 128, B_ / 64), 256, 0, stream>>>(
                hin, U_, dT, U_, nullptr, 0, bd, out + (size_t)t * F_, (long)OT * F_, pred, U_);
        }
    }
}